// Round 12
// baseline (541.424 us; speedup 1.0000x reference)
//
#include <hip/hip_runtime.h>
#include <hip/hip_bf16.h>
#include <math.h>

#define N_NODES 100000
#define N_EDGES 1600000
#define D_IN 64
#define D_HID 64
#define D_OUT 40
#define NBUCK 256
#define BSZ 391                 // nodes per bucket; 256*391 = 100096 >= N
#define P3_EPB 4096             // edges per k_place block
#define P3_GRID ((N_EDGES + P3_EPB - 1) / P3_EPB)   // 391

typedef __hip_bfloat16 bf16;

__device__ __forceinline__ float bflo(unsigned int u) {
    union { unsigned int i; float f; } c; c.i = u << 16; return c.f;
}
__device__ __forceinline__ float bfhi(unsigned int u) {
    union { unsigned int i; float f; } c; c.i = u & 0xFFFF0000u; return c.f;
}

// ---- phase 1: per-block bucket histograms (no atomics, no pre-zero) ----
__global__ __launch_bounds__(256) void k_cnt(const int* __restrict__ col,
                                             int* __restrict__ bcnt_rows) {
    __shared__ int hist[NBUCK];
    hist[threadIdx.x] = 0;
    __syncthreads();
    for (int e = blockIdx.x * 256 + threadIdx.x; e < N_EDGES; e += 256 * 256) {
        unsigned int c = (unsigned int)col[e];
        atomicAdd(&hist[c / 391u], 1);
    }
    __syncthreads();
    bcnt_rows[blockIdx.x * 256 + threadIdx.x] = hist[threadIdx.x];
}

// ---- phase 2: column-sum 256 histogram rows; scan; init fill = base ----
__global__ __launch_bounds__(256) void k_scan256(const int* __restrict__ bcnt_rows,
                                                 int* __restrict__ fill_p,
                                                 int* __restrict__ bucket_base) {
    __shared__ int sm[256];
    int t = threadIdx.x;
    int v = 0;
    for (int b = 0; b < 256; b++) v += bcnt_rows[b * 256 + t];
    sm[t] = v;
    __syncthreads();
    for (int off = 1; off < 256; off <<= 1) {
        int u = (t >= off) ? sm[t - off] : 0;
        __syncthreads();
        sm[t] += u;
        __syncthreads();
    }
    int excl = sm[t] - v;
    bucket_base[t] = excl;
    fill_p[t * 16] = excl;
    if (t == 255) bucket_base[256] = sm[255];
}

// ---- phase 3: partition edges into bucket-contiguous packed array ----
// packed part[] word: (local_c << 17) | src   (9 + 17 = 26 bits)
__global__ __launch_bounds__(256) void k_place(const int* __restrict__ ei,
                                               int* __restrict__ fill_p,
                                               int* __restrict__ part) {
    __shared__ int cnt_l[NBUCK];
    __shared__ int base_l[NBUCK];
    cnt_l[threadIdx.x] = 0;
    __syncthreads();
    int e0 = blockIdx.x * P3_EPB;
    unsigned int meta[16];                     // (b<<21)|(lc<<12)|slot
#pragma unroll
    for (int k = 0; k < 16; k++) {
        int e = e0 + k * 256 + threadIdx.x;
        if (e < N_EDGES) {
            unsigned int c = (unsigned int)ei[N_EDGES + e];
            unsigned int b = c / 391u;
            unsigned int lc = c - b * 391u;
            unsigned int slot = atomicAdd(&cnt_l[b], 1);   // slot < 4096
            meta[k] = (b << 21) | (lc << 12) | slot;
        } else meta[k] = 0xFFFFFFFFu;
    }
    __syncthreads();
    int cv = cnt_l[threadIdx.x];
    if (cv) base_l[threadIdx.x] = atomicAdd(&fill_p[threadIdx.x * 16], cv);
    __syncthreads();
#pragma unroll
    for (int k = 0; k < 16; k++) {
        if (meta[k] != 0xFFFFFFFFu) {
            int e = e0 + k * 256 + threadIdx.x;
            unsigned int b = meta[k] >> 21;
            unsigned int lc = (meta[k] >> 12) & 0x1FFu;
            unsigned int slot = meta[k] & 0xFFFu;
            unsigned int r = (unsigned int)ei[e];
            part[base_l[b] + slot] = (int)((lc << 17) | r);
        }
    }
}

// ---- phase 4: per-bucket CSR build + deg/start/dinv + per-node source sort ----
__global__ __launch_bounds__(256) void k_build(const int* __restrict__ part,
                                               const int* __restrict__ bucket_base,
                                               int* __restrict__ start,
                                               float* __restrict__ dinv,
                                               int* __restrict__ csr) {
    __shared__ int deg_l[392];
    __shared__ int excl_l[392];
    int tid = threadIdx.x;
    int b = blockIdx.x;
    int base = bucket_base[b], end = bucket_base[b + 1];
    int m = end - base;
    for (int i = tid; i < 392; i += 256) deg_l[i] = 0;
    __syncthreads();
    for (int i = tid; i < m; i += 256)
        atomicAdd(&deg_l[(unsigned int)part[base + i] >> 17], 1);
    __syncthreads();
    if (tid < 64) {
        int carry = 0;
        for (int ch = 0; ch < 7; ch++) {
            int idx = ch * 64 + tid;
            int val = (idx < 392) ? deg_l[idx] : 0;
            int incl = val;
#pragma unroll
            for (int off = 1; off < 64; off <<= 1) {
                int u = __shfl_up(incl, off, 64);
                if (tid >= off) incl += u;
            }
            if (idx < 392) excl_l[idx] = carry + incl - val;
            carry += __shfl(incl, 63, 64);
        }
    }
    __syncthreads();
    int v0 = b * BSZ;
    for (int vl = tid; vl < BSZ; vl += 256) {
        int v = v0 + vl;
        if (v < N_NODES) {
            start[v] = base + excl_l[vl];
            dinv[v] = rsqrtf((float)deg_l[vl] + 1.0f);
        }
    }
    if (b == NBUCK - 1 && tid == 0) start[N_NODES] = bucket_base[NBUCK];
    __syncthreads();
    for (int i = tid; i < 392; i += 256) deg_l[i] = 0;   // reuse as fill
    __syncthreads();
    for (int i = tid; i < m; i += 256) {
        unsigned int p = (unsigned int)part[base + i];
        unsigned int lc = p >> 17;
        int s = atomicAdd(&deg_l[lc], 1);
        csr[base + excl_l[lc] + s] = (int)(p & 0x1FFFFu);
    }
    __syncthreads();
    // per-node insertion sort by source: concurrent waves then sweep sources
    // low->high together -> clustered DRAM/L2 access in the agg kernels.
    for (int lc = tid; lc < BSZ; lc += 256) {
        int s0 = base + excl_l[lc];
        int len = deg_l[lc];                 // == segment length after fill
        for (int i = 1; i < len; i++) {
            int key = csr[s0 + i];
            int j = i - 1;
            while (j >= 0 && csr[s0 + j] > key) { csr[s0 + j + 1] = csr[s0 + j]; j--; }
            csr[s0 + j + 1] = key;
        }
    }
}

// ---- layer1 GEMM: gb[v,j] = bf16( dinv[v] * sum_k x[v,k]*W1[k,j] ) ----
__global__ __launch_bounds__(256) void k_gemm1(const float* __restrict__ x,
                                               const float* __restrict__ W,
                                               const float* __restrict__ dinv,
                                               bf16* __restrict__ gb) {
    __shared__ float Ws[64 * 64];
    __shared__ float xs[4][64];
    int tid = threadIdx.x;
    for (int i = tid; i < 64 * 64; i += 256) Ws[i] = W[i];
    int v0 = blockIdx.x * 4;
    for (int i = tid; i < 4 * 64; i += 256) xs[i >> 6][i & 63] = x[v0 * 64 + i];
    __syncthreads();
    int r = tid >> 6, j = tid & 63;
    float acc = 0.f;
#pragma unroll
    for (int k = 0; k < 64; k++) acc += xs[r][k] * Ws[k * 64 + j];
    int v = v0 + r;
    gb[v * 64 + j] = __float2bfloat16(acc * dinv[v]);
}

// ---- fused agg1 + layer2 GEMM: gather -> h (regs) -> in-wave GEMM -> g2b ----
__global__ __launch_bounds__(256) void k_agg1f(const int* __restrict__ csr,
                                               const int* __restrict__ start,
                                               const unsigned int* __restrict__ gb2,
                                               const float* __restrict__ dinv,
                                               const float* __restrict__ b1,
                                               const float* __restrict__ W2,
                                               bf16* __restrict__ g2b) {
    __shared__ float W2s[64 * 40];
    int tid = threadIdx.x;
    for (int i = tid; i < 64 * 40; i += 256) W2s[i] = W2[i];
    __syncthreads();
    int lane = tid & 63;
    int half = lane >> 5;
    int l = lane & 31;
    int v = blockIdx.x * 4 + (tid >> 6);
    int s = start[v], e2 = start[v + 1];
    float ax = 0.f, ay = 0.f;
    if (half == 0) {                       // self-loop message once
        unsigned int u = gb2[v * 32 + l];
        ax = bflo(u); ay = bfhi(u);
    }
    for (int base = s; base < e2; base += 64) {
        int cnt = e2 - base; if (cnt > 64) cnt = 64;
        int rl = (lane < cnt) ? csr[base + lane] : 0;
        int n2 = (cnt + 1) >> 1;           // wave-uniform trip count
#pragma unroll 8
        for (int i = 0; i < n2; i++) {
            int idx = 2 * i + half;
            int r = __shfl(rl, idx, 64);
            if (idx < cnt) {
                unsigned int u = gb2[r * 32 + l];
                ax += bflo(u); ay += bfhi(u);
            }
        }
    }
    ax += __shfl_xor(ax, 32, 64);          // both halves now hold full sums
    ay += __shfl_xor(ay, 32, 64);
    float d = dinv[v];
    float hx = d * ax + b1[2 * l];         // h[2l]
    float hy = d * ay + b1[2 * l + 1];     // h[2l+1]
    hx = hx > 0.f ? hx : 0.f;
    hy = hy > 0.f ? hy : 0.f;
    // in-wave GEMM: lane j (j = lane < 40) computes g2[v][j]
    float acc2 = 0.f;
#pragma unroll 8
    for (int k = 0; k < 32; k++) {
        float hk0 = __shfl(hx, k, 64);     // h[2k]
        float hk1 = __shfl(hy, k, 64);     // h[2k+1]
        if (lane < D_OUT) {
            acc2 += hk0 * W2s[(2 * k) * 40 + lane];
            acc2 += hk1 * W2s[(2 * k + 1) * 40 + lane];
        }
    }
    if (lane < D_OUT)
        g2b[(size_t)v * 40 + lane] = __float2bfloat16(acc2 * d);
}

// ---- agg2: half-wave per edge; fused bias + log_softmax -> out ----
__global__ __launch_bounds__(256) void k_agg2(const int* __restrict__ csr,
                                              const int* __restrict__ start,
                                              const unsigned int* __restrict__ g2b2,
                                              const float* __restrict__ dinv,
                                              const float* __restrict__ b2v,
                                              float* __restrict__ out) {
    int lane = threadIdx.x & 63;
    int half = lane >> 5;
    int l = lane & 31;
    int v = blockIdx.x * 4 + (threadIdx.x >> 6);
    int s = start[v], e2 = start[v + 1];
    bool act = (l < 20);
    float ax = 0.f, ay = 0.f;
    if (half == 0 && act) {
        unsigned int u = g2b2[v * 20 + l];
        ax = bflo(u); ay = bfhi(u);
    }
    for (int base = s; base < e2; base += 64) {
        int cnt = e2 - base; if (cnt > 64) cnt = 64;
        int rl = (lane < cnt) ? csr[base + lane] : 0;
        int n2 = (cnt + 1) >> 1;
#pragma unroll 8
        for (int i = 0; i < n2; i++) {
            int idx = 2 * i + half;
            int r = __shfl(rl, idx, 64);
            if (act && idx < cnt) {
                unsigned int u = g2b2[r * 20 + l];
                ax += bflo(u); ay += bfhi(u);
            }
        }
    }
    ax += __shfl_xor(ax, 32, 64);
    ay += __shfl_xor(ay, 32, 64);
    float d = dinv[v];
    float lx = act ? d * ax + b2v[2 * l] : -INFINITY;
    float ly = act ? d * ay + b2v[2 * l + 1] : -INFINITY;
    float m = fmaxf(lx, ly);
#pragma unroll
    for (int o = 16; o > 0; o >>= 1) m = fmaxf(m, __shfl_xor(m, o, 64));
    float ex = act ? (expf(lx - m) + expf(ly - m)) : 0.f;
#pragma unroll
    for (int o = 16; o > 0; o >>= 1) ex += __shfl_xor(ex, o, 64);
    float lse = m + logf(ex);
    if (half == 0 && act)
        ((float2*)(out + (size_t)v * 40))[l] = make_float2(lx - lse, ly - lse);
}

extern "C" void kernel_launch(void* const* d_in, const int* in_sizes, int n_in,
                              void* d_out, int out_size, void* d_ws, size_t ws_size,
                              hipStream_t stream) {
    const float* x  = (const float*)d_in[0];
    const int*   ei = (const int*)d_in[1];
    const float* W1 = (const float*)d_in[2];
    const float* b1 = (const float*)d_in[3];
    const float* W2 = (const float*)d_in[4];
    const float* b2 = (const float*)d_in[5];
    float* out = (float*)d_out;

    const int N = N_NODES;
    // Workspace ~36 MB (>= 68 MB proven available in R2).
    int*   part  = (int*)d_ws;                  // E
    int*   csr   = part + N_EDGES;              // E
    int*   start = csr + N_EDGES;               // N+2
    int*   bcnt  = start + N + 2;               // 256 rows x 256 (65536)
    int*   fill  = bcnt + 65536;                // 256*16 padded
    int*   bbase = fill + 4096;                 // 258
    float* dinv  = (float*)(bbase + 258);       // N
    bf16*  gb    = (bf16*)(dinv + N);           // N*64 bf16 (g1)
    bf16*  g2    = gb + (size_t)N * 64;         // N*40 bf16 (g2) — disjoint

    k_cnt<<<256, 256, 0, stream>>>(ei + N_EDGES, bcnt);
    k_scan256<<<1, 256, 0, stream>>>(bcnt, fill, bbase);
    k_place<<<P3_GRID, 256, 0, stream>>>(ei, fill, part);
    k_build<<<NBUCK, 256, 0, stream>>>(part, bbase, start, dinv, csr);
    k_gemm1<<<N / 4, 256, 0, stream>>>(x, W1, dinv, gb);
    k_agg1f<<<N / 4, 256, 0, stream>>>(csr, start, (const unsigned int*)gb, dinv, b1, W2, g2);
    k_agg2<<<N / 4, 256, 0, stream>>>(csr, start, (const unsigned int*)g2, dinv, b2, out);
}

// Round 13
// 467.849 us; speedup vs baseline: 1.1573x; 1.1573x over previous
//
#include <hip/hip_runtime.h>
#include <hip/hip_bf16.h>
#include <math.h>

#define N_NODES 100000
#define N_EDGES 1600000
#define D_IN 64
#define D_HID 64
#define D_OUT 40
#define NBUCK 256
#define BSZ 391                 // nodes per bucket; 256*391 = 100096 >= N
#define P3_EPB 4096             // edges per k_place block
#define P3_GRID ((N_EDGES + P3_EPB - 1) / P3_EPB)   // 391

typedef __hip_bfloat16 bf16;

__device__ __forceinline__ float bflo(unsigned int u) {
    union { unsigned int i; float f; } c; c.i = u << 16; return c.f;
}
__device__ __forceinline__ float bfhi(unsigned int u) {
    union { unsigned int i; float f; } c; c.i = u & 0xFFFF0000u; return c.f;
}

// ---- phase 1: per-block bucket histograms (no atomics, no pre-zero) ----
__global__ __launch_bounds__(256) void k_cnt(const int* __restrict__ col,
                                             int* __restrict__ bcnt_rows) {
    __shared__ int hist[NBUCK];
    hist[threadIdx.x] = 0;
    __syncthreads();
    for (int e = blockIdx.x * 256 + threadIdx.x; e < N_EDGES; e += 256 * 256) {
        unsigned int c = (unsigned int)col[e];
        atomicAdd(&hist[c / 391u], 1);
    }
    __syncthreads();
    bcnt_rows[blockIdx.x * 256 + threadIdx.x] = hist[threadIdx.x];
}

// ---- phase 2: column-sum 256 histogram rows; scan; init fill = base ----
__global__ __launch_bounds__(256) void k_scan256(const int* __restrict__ bcnt_rows,
                                                 int* __restrict__ fill_p,
                                                 int* __restrict__ bucket_base) {
    __shared__ int sm[256];
    int t = threadIdx.x;
    int v = 0;
    for (int b = 0; b < 256; b++) v += bcnt_rows[b * 256 + t];
    sm[t] = v;
    __syncthreads();
    for (int off = 1; off < 256; off <<= 1) {
        int u = (t >= off) ? sm[t - off] : 0;
        __syncthreads();
        sm[t] += u;
        __syncthreads();
    }
    int excl = sm[t] - v;
    bucket_base[t] = excl;
    fill_p[t * 16] = excl;
    if (t == 255) bucket_base[256] = sm[255];
}

// ---- phase 3: partition edges into bucket-contiguous packed array ----
// packed part[] word: (local_c << 17) | src   (9 + 17 = 26 bits)
__global__ __launch_bounds__(256) void k_place(const int* __restrict__ ei,
                                               int* __restrict__ fill_p,
                                               int* __restrict__ part) {
    __shared__ int cnt_l[NBUCK];
    __shared__ int base_l[NBUCK];
    cnt_l[threadIdx.x] = 0;
    __syncthreads();
    int e0 = blockIdx.x * P3_EPB;
    unsigned int meta[16];                     // (b<<21)|(lc<<12)|slot
#pragma unroll
    for (int k = 0; k < 16; k++) {
        int e = e0 + k * 256 + threadIdx.x;
        if (e < N_EDGES) {
            unsigned int c = (unsigned int)ei[N_EDGES + e];
            unsigned int b = c / 391u;
            unsigned int lc = c - b * 391u;
            unsigned int slot = atomicAdd(&cnt_l[b], 1);   // slot < 4096
            meta[k] = (b << 21) | (lc << 12) | slot;
        } else meta[k] = 0xFFFFFFFFu;
    }
    __syncthreads();
    int cv = cnt_l[threadIdx.x];
    if (cv) base_l[threadIdx.x] = atomicAdd(&fill_p[threadIdx.x * 16], cv);
    __syncthreads();
#pragma unroll
    for (int k = 0; k < 16; k++) {
        if (meta[k] != 0xFFFFFFFFu) {
            int e = e0 + k * 256 + threadIdx.x;
            unsigned int b = meta[k] >> 21;
            unsigned int lc = (meta[k] >> 12) & 0x1FFu;
            unsigned int slot = meta[k] & 0xFFFu;
            unsigned int r = (unsigned int)ei[e];
            part[base_l[b] + slot] = (int)((lc << 17) | r);
        }
    }
}

// ---- phase 4: per-bucket CSR build + deg/start/dinv (NO sort — R12 pm) ----
__global__ __launch_bounds__(256) void k_build(const int* __restrict__ part,
                                               const int* __restrict__ bucket_base,
                                               int* __restrict__ start,
                                               float* __restrict__ dinv,
                                               int* __restrict__ csr) {
    __shared__ int deg_l[392];
    __shared__ int excl_l[392];
    int tid = threadIdx.x;
    int b = blockIdx.x;
    int base = bucket_base[b], end = bucket_base[b + 1];
    int m = end - base;
    for (int i = tid; i < 392; i += 256) deg_l[i] = 0;
    __syncthreads();
    for (int i = tid; i < m; i += 256)
        atomicAdd(&deg_l[(unsigned int)part[base + i] >> 17], 1);
    __syncthreads();
    if (tid < 64) {
        int carry = 0;
        for (int ch = 0; ch < 7; ch++) {
            int idx = ch * 64 + tid;
            int val = (idx < 392) ? deg_l[idx] : 0;
            int incl = val;
#pragma unroll
            for (int off = 1; off < 64; off <<= 1) {
                int u = __shfl_up(incl, off, 64);
                if (tid >= off) incl += u;
            }
            if (idx < 392) excl_l[idx] = carry + incl - val;
            carry += __shfl(incl, 63, 64);
        }
    }
    __syncthreads();
    int v0 = b * BSZ;
    for (int vl = tid; vl < BSZ; vl += 256) {
        int v = v0 + vl;
        if (v < N_NODES) {
            start[v] = base + excl_l[vl];
            dinv[v] = rsqrtf((float)deg_l[vl] + 1.0f);
        }
    }
    if (b == NBUCK - 1 && tid == 0) start[N_NODES] = bucket_base[NBUCK];
    __syncthreads();
    for (int i = tid; i < 392; i += 256) deg_l[i] = 0;   // reuse as fill
    __syncthreads();
    for (int i = tid; i < m; i += 256) {
        unsigned int p = (unsigned int)part[base + i];
        unsigned int lc = p >> 17;
        int s = atomicAdd(&deg_l[lc], 1);
        csr[base + excl_l[lc] + s] = (int)(p & 0x1FFFFu);
    }
}

// ---- layer1 GEMM: gb[v,j] = bf16( dinv[v] * sum_k x[v,k]*W1[k,j] ) ----
__global__ __launch_bounds__(256) void k_gemm1(const float* __restrict__ x,
                                               const float* __restrict__ W,
                                               const float* __restrict__ dinv,
                                               bf16* __restrict__ gb) {
    __shared__ float Ws[64 * 64];
    __shared__ float xs[4][64];
    int tid = threadIdx.x;
    for (int i = tid; i < 64 * 64; i += 256) Ws[i] = W[i];
    int v0 = blockIdx.x * 4;
    for (int i = tid; i < 4 * 64; i += 256) xs[i >> 6][i & 63] = x[v0 * 64 + i];
    __syncthreads();
    int r = tid >> 6, j = tid & 63;
    float acc = 0.f;
#pragma unroll
    for (int k = 0; k < 64; k++) acc += xs[r][k] * Ws[k * 64 + j];
    int v = v0 + r;
    gb[v * 64 + j] = __float2bfloat16(acc * dinv[v]);
}

// ---- fused agg1 + layer2 GEMM. Inner loop: FIXED 32 iterations, fully
// unrolled, predicated — keeps ~32 gathers in flight (R12 post-mortem:
// dynamic trip count capped in-flight loads and cost ~45 µs). ----
__global__ __launch_bounds__(256) void k_agg1f(const int* __restrict__ csr,
                                               const int* __restrict__ start,
                                               const unsigned int* __restrict__ gb2,
                                               const float* __restrict__ dinv,
                                               const float* __restrict__ b1,
                                               const float* __restrict__ W2,
                                               bf16* __restrict__ g2b) {
    __shared__ float W2s[64 * 40];
    int tid = threadIdx.x;
    for (int i = tid; i < 64 * 40; i += 256) W2s[i] = W2[i];
    __syncthreads();
    int lane = tid & 63;
    int half = lane >> 5;
    int l = lane & 31;
    int v = blockIdx.x * 4 + (tid >> 6);
    int s = start[v], e2 = start[v + 1];
    float ax = 0.f, ay = 0.f;
    if (half == 0) {                       // self-loop message once
        unsigned int u = gb2[v * 32 + l];
        ax = bflo(u); ay = bfhi(u);
    }
    for (int base = s; base < e2; base += 64) {
        int cnt = e2 - base; if (cnt > 64) cnt = 64;
        int rl = (lane < cnt) ? csr[base + lane] : 0;
#pragma unroll
        for (int i = 0; i < 32; i++) {
            int idx = 2 * i + half;
            int r = __shfl(rl, idx, 64);
            if (idx < cnt) {
                unsigned int u = gb2[r * 32 + l];
                ax += bflo(u); ay += bfhi(u);
            }
        }
    }
    ax += __shfl_xor(ax, 32, 64);          // both halves now hold full sums
    ay += __shfl_xor(ay, 32, 64);
    float d = dinv[v];
    float hx = d * ax + b1[2 * l];         // h[2l]
    float hy = d * ay + b1[2 * l + 1];     // h[2l+1]
    hx = hx > 0.f ? hx : 0.f;
    hy = hy > 0.f ? hy : 0.f;
    // in-wave GEMM: lane j (j = lane < 40) computes g2[v][j]
    float acc2 = 0.f;
#pragma unroll 8
    for (int k = 0; k < 32; k++) {
        float hk0 = __shfl(hx, k, 64);     // h[2k]
        float hk1 = __shfl(hy, k, 64);     // h[2k+1]
        if (lane < D_OUT) {
            acc2 += hk0 * W2s[(2 * k) * 40 + lane];
            acc2 += hk1 * W2s[(2 * k + 1) * 40 + lane];
        }
    }
    if (lane < D_OUT)
        g2b[(size_t)v * 40 + lane] = __float2bfloat16(acc2 * d);
}

// ---- agg2: half-wave per edge; fixed-32 unrolled gather; log_softmax ----
__global__ __launch_bounds__(256) void k_agg2(const int* __restrict__ csr,
                                              const int* __restrict__ start,
                                              const unsigned int* __restrict__ g2b2,
                                              const float* __restrict__ dinv,
                                              const float* __restrict__ b2v,
                                              float* __restrict__ out) {
    int lane = threadIdx.x & 63;
    int half = lane >> 5;
    int l = lane & 31;
    int v = blockIdx.x * 4 + (threadIdx.x >> 6);
    int s = start[v], e2 = start[v + 1];
    bool act = (l < 20);
    float ax = 0.f, ay = 0.f;
    if (half == 0 && act) {
        unsigned int u = g2b2[v * 20 + l];
        ax = bflo(u); ay = bfhi(u);
    }
    for (int base = s; base < e2; base += 64) {
        int cnt = e2 - base; if (cnt > 64) cnt = 64;
        int rl = (lane < cnt) ? csr[base + lane] : 0;
#pragma unroll
        for (int i = 0; i < 32; i++) {
            int idx = 2 * i + half;
            int r = __shfl(rl, idx, 64);
            if (act && idx < cnt) {
                unsigned int u = g2b2[r * 20 + l];
                ax += bflo(u); ay += bfhi(u);
            }
        }
    }
    ax += __shfl_xor(ax, 32, 64);
    ay += __shfl_xor(ay, 32, 64);
    float d = dinv[v];
    float lx = act ? d * ax + b2v[2 * l] : -INFINITY;
    float ly = act ? d * ay + b2v[2 * l + 1] : -INFINITY;
    float m = fmaxf(lx, ly);
#pragma unroll
    for (int o = 16; o > 0; o >>= 1) m = fmaxf(m, __shfl_xor(m, o, 64));
    float ex = act ? (expf(lx - m) + expf(ly - m)) : 0.f;
#pragma unroll
    for (int o = 16; o > 0; o >>= 1) ex += __shfl_xor(ex, o, 64);
    float lse = m + logf(ex);
    if (half == 0 && act)
        ((float2*)(out + (size_t)v * 40))[l] = make_float2(lx - lse, ly - lse);
}

extern "C" void kernel_launch(void* const* d_in, const int* in_sizes, int n_in,
                              void* d_out, int out_size, void* d_ws, size_t ws_size,
                              hipStream_t stream) {
    const float* x  = (const float*)d_in[0];
    const int*   ei = (const int*)d_in[1];
    const float* W1 = (const float*)d_in[2];
    const float* b1 = (const float*)d_in[3];
    const float* W2 = (const float*)d_in[4];
    const float* b2 = (const float*)d_in[5];
    float* out = (float*)d_out;

    const int N = N_NODES;
    // Workspace ~36 MB (>= 68 MB proven available in R2).
    int*   part  = (int*)d_ws;                  // E
    int*   csr   = part + N_EDGES;              // E
    int*   start = csr + N_EDGES;               // N+2
    int*   bcnt  = start + N + 2;               // 256 rows x 256 (65536)
    int*   fill  = bcnt + 65536;                // 256*16 padded
    int*   bbase = fill + 4096;                 // 258
    float* dinv  = (float*)(bbase + 258);       // N
    bf16*  gb    = (bf16*)(dinv + N);           // N*64 bf16 (g1)
    bf16*  g2    = gb + (size_t)N * 64;         // N*40 bf16 (g2) — disjoint

    k_cnt<<<256, 256, 0, stream>>>(ei + N_EDGES, bcnt);
    k_scan256<<<1, 256, 0, stream>>>(bcnt, fill, bbase);
    k_place<<<P3_GRID, 256, 0, stream>>>(ei, fill, part);
    k_build<<<NBUCK, 256, 0, stream>>>(part, bbase, start, dinv, csr);
    k_gemm1<<<N / 4, 256, 0, stream>>>(x, W1, dinv, gb);
    k_agg1f<<<N / 4, 256, 0, stream>>>(csr, start, (const unsigned int*)gb, dinv, b1, W2, g2);
    k_agg2<<<N / 4, 256, 0, stream>>>(csr, start, (const unsigned int*)g2, dinv, b2, out);
}

// Round 14
// 395.647 us; speedup vs baseline: 1.3685x; 1.1825x over previous
//
#include <hip/hip_runtime.h>
#include <hip/hip_bf16.h>
#include <math.h>

#define N_NODES 100000
#define N_EDGES 1600000
#define D_IN 64
#define D_HID 64
#define D_OUT 40
#define NBUCK 256
#define BSZ 391                 // nodes per bucket; 256*391 = 100096 >= N
#define P3_EPB 4096             // edges per k_place block
#define P3_GRID ((N_EDGES + P3_EPB - 1) / P3_EPB)   // 391

typedef __hip_bfloat16 bf16;

__device__ __forceinline__ float bflo(unsigned int u) {
    union { unsigned int i; float f; } c; c.i = u << 16; return c.f;
}
__device__ __forceinline__ float bfhi(unsigned int u) {
    union { unsigned int i; float f; } c; c.i = u & 0xFFFF0000u; return c.f;
}
__device__ __forceinline__ unsigned int packbf(float x, float y) {
    union { bf16 b; unsigned short u; } cl, ch;
    cl.b = __float2bfloat16(x); ch.b = __float2bfloat16(y);
    return ((unsigned int)ch.u << 16) | cl.u;
}

// ---- phase 1: per-block bucket histograms (no atomics, no pre-zero) ----
__global__ __launch_bounds__(256) void k_cnt(const int* __restrict__ col,
                                             int* __restrict__ bcnt_rows) {
    __shared__ int hist[NBUCK];
    hist[threadIdx.x] = 0;
    __syncthreads();
    for (int e = blockIdx.x * 256 + threadIdx.x; e < N_EDGES; e += 256 * 256) {
        unsigned int c = (unsigned int)col[e];
        atomicAdd(&hist[c / 391u], 1);
    }
    __syncthreads();
    bcnt_rows[blockIdx.x * 256 + threadIdx.x] = hist[threadIdx.x];
}

// ---- phase 2: column-sum 256 histogram rows; scan; init fill = base ----
__global__ __launch_bounds__(256) void k_scan256(const int* __restrict__ bcnt_rows,
                                                 int* __restrict__ fill_p,
                                                 int* __restrict__ bucket_base) {
    __shared__ int sm[256];
    int t = threadIdx.x;
    int v = 0;
    for (int b = 0; b < 256; b++) v += bcnt_rows[b * 256 + t];
    sm[t] = v;
    __syncthreads();
    for (int off = 1; off < 256; off <<= 1) {
        int u = (t >= off) ? sm[t - off] : 0;
        __syncthreads();
        sm[t] += u;
        __syncthreads();
    }
    int excl = sm[t] - v;
    bucket_base[t] = excl;
    fill_p[t * 16] = excl;
    if (t == 255) bucket_base[256] = sm[255];
}

// ---- phase 3: partition edges into bucket-contiguous packed array ----
// packed part[] word: (local_c << 17) | src   (9 + 17 = 26 bits)
__global__ __launch_bounds__(256) void k_place(const int* __restrict__ ei,
                                               int* __restrict__ fill_p,
                                               int* __restrict__ part) {
    __shared__ int cnt_l[NBUCK];
    __shared__ int base_l[NBUCK];
    cnt_l[threadIdx.x] = 0;
    __syncthreads();
    int e0 = blockIdx.x * P3_EPB;
    unsigned int meta[16];                     // (b<<21)|(lc<<12)|slot
#pragma unroll
    for (int k = 0; k < 16; k++) {
        int e = e0 + k * 256 + threadIdx.x;
        if (e < N_EDGES) {
            unsigned int c = (unsigned int)ei[N_EDGES + e];
            unsigned int b = c / 391u;
            unsigned int lc = c - b * 391u;
            unsigned int slot = atomicAdd(&cnt_l[b], 1);   // slot < 4096
            meta[k] = (b << 21) | (lc << 12) | slot;
        } else meta[k] = 0xFFFFFFFFu;
    }
    __syncthreads();
    int cv = cnt_l[threadIdx.x];
    if (cv) base_l[threadIdx.x] = atomicAdd(&fill_p[threadIdx.x * 16], cv);
    __syncthreads();
#pragma unroll
    for (int k = 0; k < 16; k++) {
        if (meta[k] != 0xFFFFFFFFu) {
            int e = e0 + k * 256 + threadIdx.x;
            unsigned int b = meta[k] >> 21;
            unsigned int lc = (meta[k] >> 12) & 0x1FFu;
            unsigned int slot = meta[k] & 0xFFFu;
            unsigned int r = (unsigned int)ei[e];
            part[base_l[b] + slot] = (int)((lc << 17) | r);
        }
    }
}

// ---- phase 4: per-bucket CSR build + deg/start/dinv ----
__global__ __launch_bounds__(256) void k_build(const int* __restrict__ part,
                                               const int* __restrict__ bucket_base,
                                               int* __restrict__ start,
                                               float* __restrict__ dinv,
                                               int* __restrict__ csr) {
    __shared__ int deg_l[392];
    __shared__ int excl_l[392];
    int tid = threadIdx.x;
    int b = blockIdx.x;
    int base = bucket_base[b], end = bucket_base[b + 1];
    int m = end - base;
    for (int i = tid; i < 392; i += 256) deg_l[i] = 0;
    __syncthreads();
    for (int i = tid; i < m; i += 256)
        atomicAdd(&deg_l[(unsigned int)part[base + i] >> 17], 1);
    __syncthreads();
    if (tid < 64) {
        int carry = 0;
        for (int ch = 0; ch < 7; ch++) {
            int idx = ch * 64 + tid;
            int val = (idx < 392) ? deg_l[idx] : 0;
            int incl = val;
#pragma unroll
            for (int off = 1; off < 64; off <<= 1) {
                int u = __shfl_up(incl, off, 64);
                if (tid >= off) incl += u;
            }
            if (idx < 392) excl_l[idx] = carry + incl - val;
            carry += __shfl(incl, 63, 64);
        }
    }
    __syncthreads();
    int v0 = b * BSZ;
    for (int vl = tid; vl < BSZ; vl += 256) {
        int v = v0 + vl;
        if (v < N_NODES) {
            start[v] = base + excl_l[vl];
            dinv[v] = rsqrtf((float)deg_l[vl] + 1.0f);
        }
    }
    if (b == NBUCK - 1 && tid == 0) start[N_NODES] = bucket_base[NBUCK];
    __syncthreads();
    for (int i = tid; i < 392; i += 256) deg_l[i] = 0;   // reuse as fill
    __syncthreads();
    for (int i = tid; i < m; i += 256) {
        unsigned int p = (unsigned int)part[base + i];
        unsigned int lc = p >> 17;
        int s = atomicAdd(&deg_l[lc], 1);
        csr[base + excl_l[lc] + s] = (int)(p & 0x1FFFFu);
    }
}

// ---- layer1 GEMM: gb[v,j] = bf16( dinv[v] * sum_k x[v,k]*W1[k,j] ) ----
__global__ __launch_bounds__(256) void k_gemm1(const float* __restrict__ x,
                                               const float* __restrict__ W,
                                               const float* __restrict__ dinv,
                                               bf16* __restrict__ gb) {
    __shared__ float Ws[64 * 64];
    __shared__ float xs[4][64];
    int tid = threadIdx.x;
    for (int i = tid; i < 64 * 64; i += 256) Ws[i] = W[i];
    int v0 = blockIdx.x * 4;
    for (int i = tid; i < 4 * 64; i += 256) xs[i >> 6][i & 63] = x[v0 * 64 + i];
    __syncthreads();
    int r = tid >> 6, j = tid & 63;
    float acc = 0.f;
#pragma unroll
    for (int k = 0; k < 64; k++) acc += xs[r][k] * Ws[k * 64 + j];
    int v = v0 + r;
    gb[v * 64 + j] = __float2bfloat16(acc * dinv[v]);
}

// ---- agg1 (UNFUSED — R13 pm: fusion's per-block W2 staging cost ~2x):
// half-wave per edge, fixed-32 inner loop, unroll 8 (R9-proven variant);
// writes h as packed bf16 pairs ----
__global__ __launch_bounds__(256) void k_agg1(const int* __restrict__ csr,
                                              const int* __restrict__ start,
                                              const unsigned int* __restrict__ gb2,
                                              const float* __restrict__ dinv,
                                              const float* __restrict__ b1,
                                              unsigned int* __restrict__ h2) {
    int lane = threadIdx.x & 63;
    int half = lane >> 5;
    int l = lane & 31;
    int v = blockIdx.x * 4 + (threadIdx.x >> 6);
    int s = start[v], e2 = start[v + 1];
    float ax = 0.f, ay = 0.f;
    if (half == 0) {                      // self-loop message once
        unsigned int u = gb2[v * 32 + l];
        ax = bflo(u); ay = bfhi(u);
    }
    for (int base = s; base < e2; base += 64) {
        int cnt = e2 - base; if (cnt > 64) cnt = 64;
        int rl = (lane < cnt) ? csr[base + lane] : 0;
#pragma unroll 8
        for (int i = 0; i < 32; i++) {
            int idx = 2 * i + half;
            int r = __shfl(rl, idx, 64);
            if (idx < cnt) {
                unsigned int u = gb2[r * 32 + l];
                ax += bflo(u); ay += bfhi(u);
            }
        }
    }
    ax += __shfl_xor(ax, 32, 64);
    ay += __shfl_xor(ay, 32, 64);
    float d = dinv[v];
    float hx = d * ax + b1[2 * l];
    float hy = d * ay + b1[2 * l + 1];
    hx = hx > 0.f ? hx : 0.f;
    hy = hy > 0.f ? hy : 0.f;
    if (half == 0) h2[v * 32 + l] = packbf(hx, hy);
}

// ---- layer2 GEMM (separate, LDS-staged): g2b = bf16(dinv * h@W2) ----
__global__ __launch_bounds__(256) void k_gemm2(const unsigned int* __restrict__ h2,
                                               const float* __restrict__ W,
                                               const float* __restrict__ dinv,
                                               bf16* __restrict__ g2b) {
    __shared__ float Ws[64 * 40];
    __shared__ float hs[4][64];
    int tid = threadIdx.x;
    for (int i = tid; i < 64 * 40; i += 256) Ws[i] = W[i];
    int v0 = blockIdx.x * 4;
    if (tid < 128) {
        unsigned int u = h2[v0 * 32 + tid];
        hs[tid >> 5][(tid & 31) * 2] = bflo(u);
        hs[tid >> 5][(tid & 31) * 2 + 1] = bfhi(u);
    }
    __syncthreads();
    int r = tid >> 6, j = tid & 63;
    if (j < 40) {
        float acc = 0.f;
#pragma unroll
        for (int k = 0; k < 64; k++) acc += hs[r][k] * Ws[k * 40 + j];
        int v = v0 + r;
        g2b[v * 40 + j] = __float2bfloat16(acc * dinv[v]);
    }
}

// ---- agg2: half-wave per edge; fixed-32 unroll-8 gather; log_softmax ----
__global__ __launch_bounds__(256) void k_agg2(const int* __restrict__ csr,
                                              const int* __restrict__ start,
                                              const unsigned int* __restrict__ g2b2,
                                              const float* __restrict__ dinv,
                                              const float* __restrict__ b2v,
                                              float* __restrict__ out) {
    int lane = threadIdx.x & 63;
    int half = lane >> 5;
    int l = lane & 31;
    int v = blockIdx.x * 4 + (threadIdx.x >> 6);
    int s = start[v], e2 = start[v + 1];
    bool act = (l < 20);
    float ax = 0.f, ay = 0.f;
    if (half == 0 && act) {
        unsigned int u = g2b2[v * 20 + l];
        ax = bflo(u); ay = bfhi(u);
    }
    for (int base = s; base < e2; base += 64) {
        int cnt = e2 - base; if (cnt > 64) cnt = 64;
        int rl = (lane < cnt) ? csr[base + lane] : 0;
#pragma unroll 8
        for (int i = 0; i < 32; i++) {
            int idx = 2 * i + half;
            int r = __shfl(rl, idx, 64);
            if (act && idx < cnt) {
                unsigned int u = g2b2[r * 20 + l];
                ax += bflo(u); ay += bfhi(u);
            }
        }
    }
    ax += __shfl_xor(ax, 32, 64);
    ay += __shfl_xor(ay, 32, 64);
    float d = dinv[v];
    float lx = act ? d * ax + b2v[2 * l] : -INFINITY;
    float ly = act ? d * ay + b2v[2 * l + 1] : -INFINITY;
    float m = fmaxf(lx, ly);
#pragma unroll
    for (int o = 16; o > 0; o >>= 1) m = fmaxf(m, __shfl_xor(m, o, 64));
    float ex = act ? (expf(lx - m) + expf(ly - m)) : 0.f;
#pragma unroll
    for (int o = 16; o > 0; o >>= 1) ex += __shfl_xor(ex, o, 64);
    float lse = m + logf(ex);
    if (half == 0 && act)
        ((float2*)(out + (size_t)v * 40))[l] = make_float2(lx - lse, ly - lse);
}

extern "C" void kernel_launch(void* const* d_in, const int* in_sizes, int n_in,
                              void* d_out, int out_size, void* d_ws, size_t ws_size,
                              hipStream_t stream) {
    const float* x  = (const float*)d_in[0];
    const int*   ei = (const int*)d_in[1];
    const float* W1 = (const float*)d_in[2];
    const float* b1 = (const float*)d_in[3];
    const float* W2 = (const float*)d_in[4];
    const float* b2 = (const float*)d_in[5];
    float* out = (float*)d_out;

    const int N = N_NODES;
    // Workspace ~47.5 MB (<= 59 MB proven available in R6).
    int*   part  = (int*)d_ws;                  // E
    int*   csr   = part + N_EDGES;              // E
    int*   start = csr + N_EDGES;               // N+2
    int*   bcnt  = start + N + 2;               // 256 rows x 256 (65536)
    int*   fill  = bcnt + 65536;                // 256*16 padded
    int*   bbase = fill + 4096;                 // 258
    float* dinv  = (float*)(bbase + 258);       // N
    bf16*  gb    = (bf16*)(dinv + N);           // N*64 bf16 (g1)
    bf16*  g2    = gb + (size_t)N * 64;         // N*40 bf16 (g2)
    unsigned int* h2 = (unsigned int*)(g2 + (size_t)N * 40);  // N*32 (bf16-pair h)

    k_cnt<<<256, 256, 0, stream>>>(ei + N_EDGES, bcnt);
    k_scan256<<<1, 256, 0, stream>>>(bcnt, fill, bbase);
    k_place<<<P3_GRID, 256, 0, stream>>>(ei, fill, part);
    k_build<<<NBUCK, 256, 0, stream>>>(part, bbase, start, dinv, csr);
    k_gemm1<<<N / 4, 256, 0, stream>>>(x, W1, dinv, gb);
    k_agg1<<<N / 4, 256, 0, stream>>>(csr, start, (const unsigned int*)gb, dinv, b1, h2);
    k_gemm2<<<N / 4, 256, 0, stream>>>(h2, W2, dinv, g2);
    k_agg2<<<N / 4, 256, 0, stream>>>(csr, start, (const unsigned int*)g2, dinv, b2, out);
}